// Round 7
// baseline (140.567 us; speedup 1.0000x reference)
//
#include <hip/hip_runtime.h>

#define SDIM 500
#define DDIM 64
#define NT   256

__device__ __forceinline__ unsigned ford(float x) {
    unsigned u = __float_as_uint(x);
    return u ^ ((unsigned)((int)u >> 31) | 0x80000000u);
}

__device__ __forceinline__ float dot16(float4 a0, float4 a1, float4 a2, float4 a3,
                                       float4 b0, float4 b1, float4 b2, float4 b3) {
    return a0.x*b0.x + a0.y*b0.y + a0.z*b0.z + a0.w*b0.w
         + a1.x*b1.x + a1.y*b1.y + a1.z*b1.z + a1.w*b1.w
         + a2.x*b2.x + a2.y*b2.y + a2.z*b2.z + a2.w*b2.w
         + a3.x*b3.x + a3.y*b3.y + a3.z*b3.z + a3.w*b3.w;
}

// One row per 256-thread block. 4 waves cooperate on the gather/score phase
// (coalesced, round-3 structure, 16K waves machine-wide for latency hiding);
// then waves 1-3 EXIT and wave 0 alone runs selection wave-locally
// (shuffle/ballot + intra-wave-ordered LDS, no __syncthreads). Freed wave
// slots refill with other blocks' gather phases.
__global__ __launch_bounds__(NT) void rs_main(
    const int* __restrict__ need_replace,    // (N,2)
    const float* __restrict__ union_feature, // (N,128)
    const float* __restrict__ all_items,     // (n_items,64)
    const int* __restrict__ sample_items,    // (n_users,500)
    const float* __restrict__ Wm,            // (64,128)
    const float* __restrict__ bv,            // (64)
    const float* __restrict__ gumbel_u,      // (N,500)
    float* __restrict__ out_items,           // (N)
    float* __restrict__ out_feat,            // (N,64)
    int* __restrict__ ws_acc)                // [0]=sum(pos), [1]=sum|pos-250|
{
    __shared__ __align__(16) float s_uf[128];
    __shared__ __align__(16) float s_uif[DDIM];
    __shared__ unsigned s_fv[SDIM];
    __shared__ float    s_key[SDIM];
    __shared__ int      s_samp[SDIM];
    __shared__ int      s_hist[256];

    const int n    = blockIdx.x;
    const int tid  = threadIdx.x;
    const int wid  = tid >> 6;
    const int lane = tid & 63;
    const int part = tid & 3, quad = tid >> 2;

    const int user = need_replace[2 * n];
    const int item = need_replace[2 * n + 1];
    const int*   samp_row = sample_items + (long)user * SDIM;
    const float* gur      = gumbel_u + (long)n * SDIM;

    // ---- stage (coalesced) ----
    if (tid < 128) s_uf[tid] = union_feature[(long)n * 128 + tid];
    for (int s = tid; s < SDIM; s += NT) s_samp[s] = samp_row[s];
    // item-embedding fragment (16 floats/lane by part; L1-broadcast across quads)
    const float4* ir = (const float4*)(all_items + (long)item * DDIM) + part * 4;
    const float4 wiA = ir[0], wiB = ir[1], wiC = ir[2], wiD = ir[3];
    __syncthreads();

    // ---- uif = W @ uf + b : 4 lanes per output row ----
    {
        const int row = quad;            // 0..63
        const float4* wr4 = (const float4*)(Wm + (long)row * 128);
        const float4* uf4 = (const float4*)s_uf;
        float acc = 0.f;
        #pragma unroll
        for (int q = 0; q < 8; ++q) {
            float4 w4 = wr4[part + q * 4];
            float4 u4 = uf4[part + q * 4];
            acc += w4.x * u4.x + w4.y * u4.y + w4.z * u4.z + w4.w * u4.w;
        }
        acc += __shfl_xor(acc, 1);
        acc += __shfl_xor(acc, 2);
        if (part == 0) s_uif[row] = acc + bv[row];
    }
    __syncthreads();
    const float4* ur = (const float4*)s_uif + part * 4;
    const float4 wuA = ur[0], wuB = ur[1], wuC = ur[2], wuD = ur[3];

    // ---- score phase: quad per sample row (coalesced 256B/row) ----
    for (int s0 = 0; s0 < SDIM; s0 += NT / 4) {
        const int s = s0 + quad;
        float a0 = 0.f, a1 = 0.f;
        if (s < SDIM) {
            const float4* fr = (const float4*)(all_items + (long)s_samp[s] * DDIM) + part * 4;
            float4 f0 = fr[0], f1 = fr[1], f2 = fr[2], f3 = fr[3];
            a0 = dot16(f0, f1, f2, f3, wiA, wiB, wiC, wiD);
            a1 = dot16(f0, f1, f2, f3, wuA, wuB, wuC, wuD);
        }
        a0 += __shfl_xor(a0, 1); a0 += __shfl_xor(a0, 2);
        a1 += __shfl_xor(a1, 1); a1 += __shfl_xor(a1, 2);
        if (s < SDIM && part == 0) { s_fv[s] = ford(a0); s_key[s] = a1; }
    }
    __syncthreads();

    // ---- waves 1-3 are done: free their slots for other blocks' gathers ----
    if (wid != 0) return;

    // ======================= wave 0 only below =======================

    // ---- argmax of replace_score + gumbel (first-max tie-break) ----
    float bvv = -__builtin_inff();
    int   bii = SDIM;
    #pragma unroll
    for (int c = 0; c < 8; ++c) {
        const int s = c * 64 + lane;
        if (s < SDIM) {
            float u = gur[s];
            float g = -logf(-logf(u * (1.0f - 2e-7f) + 1e-7f));
            float v = s_key[s] + g;
            if (v > bvv) { bvv = v; bii = s; }   // ascending s keeps first max
        }
    }
    #pragma unroll
    for (int off = 1; off < 64; off <<= 1) {
        float v2 = __shfl_xor(bvv, off);
        int   i2 = __shfl_xor(bii, off);
        if (v2 > bvv || (v2 == bvv && i2 < bii)) { bvv = v2; bii = i2; }
    }
    const int k = bii;

    // ---- overlap: feature output = all_items[samp[k]] ----
    const int src_item = s_samp[k];
    out_feat[(long)n * DDIM + lane] = all_items[(long)src_item * DDIM + lane];

    // ---- rank_k = stable rank of element k ----
    int rank_k = 0;
    {
        const unsigned fvk = s_fv[k];
        #pragma unroll
        for (int c = 0; c < 8; ++c) {
            const int s = c * 64 + lane;
            if (s < SDIM) {
                unsigned v = s_fv[s];
                rank_k += (int)((v < fvk) | ((v == fvk) & (s < k)));
            }
        }
        #pragma unroll
        for (int off = 1; off < 64; off <<= 1) rank_k += __shfl_xor(rank_k, off);
    }

    // ---- radix-select: j* = index of k-th smallest (stable), wave-local ----
    unsigned prefix = 0;
    int krem = k;
    #pragma unroll
    for (int pass = 0; pass < 4; ++pass) {
        const int shift = 24 - 8 * pass;
        s_hist[lane] = 0; s_hist[lane + 64] = 0; s_hist[lane + 128] = 0; s_hist[lane + 192] = 0;
        __builtin_amdgcn_wave_barrier();   // intra-wave DS ops are ordered; fence compiler
        const unsigned himask = pass ? (0xFFFFFFFFu << (shift + 8)) : 0u;
        #pragma unroll
        for (int c = 0; c < 8; ++c) {
            const int s = c * 64 + lane;
            if (s < SDIM) {
                unsigned v = s_fv[s];
                if ((v & himask) == prefix) atomicAdd(&s_hist[(v >> shift) & 0xFF], 1);
            }
        }
        __builtin_amdgcn_wave_barrier();
        int h0 = s_hist[4 * lane], h1 = s_hist[4 * lane + 1];
        int h2 = s_hist[4 * lane + 2], h3 = s_hist[4 * lane + 3];
        int s4 = h0 + h1 + h2 + h3, inc = s4;
        #pragma unroll
        for (int off = 1; off < 64; off <<= 1) {
            int t = __shfl_up(inc, off);
            if (lane >= off) inc += t;
        }
        const int base = inc - s4;
        const bool found = (krem >= base) && (krem < inc);
        int selb = 0, selk = 0;
        if (found) {
            if      (krem < base + h0)           { selb = 4 * lane;     selk = krem - base; }
            else if (krem < base + h0 + h1)      { selb = 4 * lane + 1; selk = krem - base - h0; }
            else if (krem < base + h0 + h1 + h2) { selb = 4 * lane + 2; selk = krem - base - h0 - h1; }
            else                                 { selb = 4 * lane + 3; selk = krem - base - h0 - h1 - h2; }
        }
        unsigned long long m = __ballot(found);
        int srcl = __ffsll((long long)m) - 1;
        selb = __shfl(selb, srcl);
        selk = __shfl(selk, srcl);
        prefix |= ((unsigned)selb) << shift;
        krem = selk;
        __builtin_amdgcn_wave_barrier();
    }

    // ---- stable tie resolution among fv==prefix by original index ----
    int jstar = -1;
    {
        int basec = 0;
        #pragma unroll
        for (int c = 0; c < 8; ++c) {
            const int s = c * 64 + lane;
            const bool m = (s < SDIM) && (s_fv[s] == prefix);
            unsigned long long mask = __ballot(m);
            int myrank = __popcll(mask & ((1ull << lane) - 1ull));
            if (m && (basec + myrank == krem)) jstar = s;
            basec += __popcll(mask);
        }
        unsigned long long mm = __ballot(jstar >= 0);
        int srcl = __ffsll((long long)mm) - 1;
        jstar = __shfl(jstar, srcl);
    }

    // ---- outputs ----
    if (lane == 0) {
        out_items[n] = (float)s_samp[jstar];
        const int pos = rank_k + 1;            // similarity = pos/500
        atomicAdd(&ws_acc[0], pos);            // mean(similarity)
        atomicAdd(&ws_acc[1], abs(pos - 250)); // |sim-0.5| = |pos-250|/500
    }
}

__global__ __launch_bounds__(64) void rs_fin(const int* __restrict__ ws_acc,
                                             float* __restrict__ out_scal, int N)
{
    if (threadIdx.x == 0) {
        const double denom = (double)SDIM * (double)N;
        out_scal[0] = (float)((double)ws_acc[1] / denom);  // similarity_loss
        out_scal[1] = (float)((double)ws_acc[0] / denom);  // mean(similarity)
    }
}

extern "C" void kernel_launch(void* const* d_in, const int* in_sizes, int n_in,
                              void* d_out, int out_size, void* d_ws, size_t ws_size,
                              hipStream_t stream) {
    const int*   need_replace  = (const int*)d_in[0];
    const float* union_feature = (const float*)d_in[1];
    const float* all_items     = (const float*)d_in[2];
    const int*   sample_items  = (const int*)d_in[3];
    const float* Wm            = (const float*)d_in[4];
    const float* bv            = (const float*)d_in[5];
    const float* gumbel_u      = (const float*)d_in[6];

    const int N = in_sizes[0] / 2;  // 4096

    float* out       = (float*)d_out;
    float* out_items = out;                       // N
    float* out_feat  = out + N;                   // N*64
    float* out_scal  = out + N + (long)N * DDIM;  // 2 scalars
    int*   ws_acc    = (int*)d_ws;                // 2 ints

    hipMemsetAsync(ws_acc, 0, 2 * sizeof(int), stream);
    rs_main<<<N, NT, 0, stream>>>(need_replace, union_feature, all_items,
                                  sample_items, Wm, bv, gumbel_u,
                                  out_items, out_feat, ws_acc);
    rs_fin<<<1, 64, 0, stream>>>(ws_acc, out_scal, N);
}

// Round 8
// 138.213 us; speedup vs baseline: 1.0170x; 1.0170x over previous
//
#include <hip/hip_runtime.h>

#define SDIM 500
#define DDIM 64
#define NT   256

__device__ __forceinline__ unsigned ford(float x) {
    unsigned u = __float_as_uint(x);
    return u ^ ((unsigned)((int)u >> 31) | 0x80000000u);
}

__device__ __forceinline__ float dot16(float4 a0, float4 a1, float4 a2, float4 a3,
                                       float4 b0, float4 b1, float4 b2, float4 b3) {
    return a0.x*b0.x + a0.y*b0.y + a0.z*b0.z + a0.w*b0.w
         + a1.x*b1.x + a1.y*b1.y + a1.z*b1.z + a1.w*b1.w
         + a2.x*b2.x + a2.y*b2.y + a2.z*b2.z + a2.w*b2.w
         + a3.x*b3.x + a3.y*b3.y + a3.z*b3.z + a3.w*b3.w;
}

// Round-3 structure (measured optimum: one row per 256-thread block, 4 waves
// cooperate through all phases) + ONE lever: depth-1 prefetch in the score
// gather loop. Scalars via integer atomics + 1-thread finalize.
__global__ __launch_bounds__(NT) void rs_main(
    const int* __restrict__ need_replace,    // (N,2)
    const float* __restrict__ union_feature, // (N,128)
    const float* __restrict__ all_items,     // (n_items,64)
    const int* __restrict__ sample_items,    // (n_users,500)
    const float* __restrict__ Wm,            // (64,128)
    const float* __restrict__ bv,            // (64)
    const float* __restrict__ gumbel_u,      // (N,500)
    float* __restrict__ out_items,           // (N)
    float* __restrict__ out_feat,            // (N,64)
    int* __restrict__ ws_acc)                // [0]=sum(pos), [1]=sum|pos-250|
{
    __shared__ __align__(16) float s_uf[128];
    __shared__ __align__(16) float s_uif[DDIM];
    __shared__ unsigned s_fv[SDIM];   // order-preserving uint of rank_score
    __shared__ float    s_key[SDIM];  // replace_score (raw, pre-gumbel)
    __shared__ int      s_samp[SDIM];
    __shared__ int      s_hist[256];
    __shared__ float    s_mv[4];
    __shared__ int      s_mi[4];
    __shared__ int      s_cnt4[4];
    __shared__ int      s_selb, s_selk, s_k, s_tn;
    __shared__ int      s_tbuf[64];

    const int n    = blockIdx.x;
    const int tid  = threadIdx.x;
    const int wid  = tid >> 6;
    const int part = tid & 3, quad = tid >> 2;

    const int user = need_replace[2 * n];
    const int item = need_replace[2 * n + 1];
    const int*   samp_row = sample_items + (long)user * SDIM;
    const float* gur      = gumbel_u + (long)n * SDIM;

    // ---- stage (coalesced) ----
    if (tid < 128) s_uf[tid] = union_feature[(long)n * 128 + tid];
    for (int s = tid; s < SDIM; s += NT) s_samp[s] = samp_row[s];
    const float4* ir = (const float4*)(all_items + (long)item * DDIM) + part * 4;
    const float4 wiA = ir[0], wiB = ir[1], wiC = ir[2], wiD = ir[3];
    __syncthreads();

    // ---- uif = W @ uf + b : 4 lanes per output row ----
    {
        const float4* wr4 = (const float4*)(Wm + (long)quad * 128);
        const float4* uf4 = (const float4*)s_uf;
        float acc = 0.f;
        #pragma unroll
        for (int q = 0; q < 8; ++q) {
            float4 w4 = wr4[part + q * 4];
            float4 u4 = uf4[part + q * 4];
            acc += w4.x * u4.x + w4.y * u4.y + w4.z * u4.z + w4.w * u4.w;
        }
        acc += __shfl_xor(acc, 1);
        acc += __shfl_xor(acc, 2);
        if (part == 0) s_uif[quad] = acc + bv[quad];
    }
    __syncthreads();
    const float4* ur = (const float4*)s_uif + part * 4;
    const float4 wuA = ur[0], wuB = ur[1], wuC = ur[2], wuD = ur[3];

    // ---- score phase: quad per sample row, depth-1 prefetched gathers ----
    float4 f0, f1, f2, f3;
    {
        const float4* p = (const float4*)(all_items + (long)s_samp[quad] * DDIM) + part * 4;
        f0 = p[0]; f1 = p[1]; f2 = p[2]; f3 = p[3];
    }
    #pragma unroll
    for (int i = 0; i < 8; ++i) {
        const int s = i * 64 + quad;
        float4 g0 = f0, g1 = f1, g2 = f2, g3 = f3;
        if (i < 7) {
            const int sn = s + 64;
            const bool actn = (sn < SDIM);
            const int idxn = s_samp[actn ? sn : 0];
            const float4* q = (const float4*)(all_items + (long)idxn * DDIM) + part * 4;
            if (actn) { g0 = q[0]; g1 = q[1]; g2 = q[2]; g3 = q[3]; }
        }
        const bool act = (s < SDIM);
        float a0 = dot16(f0, f1, f2, f3, wiA, wiB, wiC, wiD);
        float a1 = dot16(f0, f1, f2, f3, wuA, wuB, wuC, wuD);
        a0 += __shfl_xor(a0, 1); a0 += __shfl_xor(a0, 2);
        a1 += __shfl_xor(a1, 1); a1 += __shfl_xor(a1, 2);
        if (act && part == 0) { s_fv[s] = ford(a0); s_key[s] = a1; }
        f0 = g0; f1 = g1; f2 = g2; f3 = g3;
    }
    __syncthreads();

    // ---- argmax of replace_score + gumbel (first-max tie-break) ----
    {
        float bvv = -__builtin_inff();
        int   bii = SDIM;
        for (int s = tid; s < SDIM; s += NT) {
            float u = gur[s];
            float g = -logf(-logf(u * (1.0f - 2e-7f) + 1e-7f));
            float v = s_key[s] + g;
            if (v > bvv) { bvv = v; bii = s; }
        }
        #pragma unroll
        for (int off = 1; off < 64; off <<= 1) {
            float v2 = __shfl_xor(bvv, off); int i2 = __shfl_xor(bii, off);
            if (v2 > bvv || (v2 == bvv && i2 < bii)) { bvv = v2; bii = i2; }
        }
        if ((tid & 63) == 0) { s_mv[wid] = bvv; s_mi[wid] = bii; }
        __syncthreads();
        if (tid == 0) {
            float mv = s_mv[0]; int mi = s_mi[0];
            #pragma unroll
            for (int w = 1; w < 4; ++w) {
                float v2 = s_mv[w]; int i2 = s_mi[w];
                if (v2 > mv || (v2 == mv && i2 < mi)) { mv = v2; mi = i2; }
            }
            s_k = mi;
        }
        __syncthreads();
    }
    const int k = s_k;

    // ---- overlap: feature output = all_items[samp[k]] ----
    {
        const int src = s_samp[k];
        if (tid < DDIM)
            out_feat[(long)n * DDIM + tid] = all_items[(long)src * DDIM + tid];
    }

    // ---- rank_k = stable rank of element k ----
    int rank_k;
    {
        const unsigned fvk = s_fv[k];
        int cnt = 0;
        for (int s = tid; s < SDIM; s += NT) {
            unsigned v = s_fv[s];
            cnt += (int)((v < fvk) | ((v == fvk) & (s < k)));
        }
        #pragma unroll
        for (int off = 1; off < 64; off <<= 1) cnt += __shfl_xor(cnt, off);
        if ((tid & 63) == 0) s_cnt4[wid] = cnt;
        __syncthreads();
        rank_k = s_cnt4[0] + s_cnt4[1] + s_cnt4[2] + s_cnt4[3];
    }

    // ---- radix-select: j* = index of k-th smallest (stable) ----
    unsigned prefix = 0;
    int krem = k;
    for (int pass = 0; pass < 4; ++pass) {
        const int shift = 24 - 8 * pass;
        s_hist[tid] = 0;
        __syncthreads();
        const unsigned himask = pass ? (0xFFFFFFFFu << (shift + 8)) : 0u;
        for (int s = tid; s < SDIM; s += NT) {
            unsigned v = s_fv[s];
            if ((v & himask) == prefix) atomicAdd(&s_hist[(v >> shift) & 0xFF], 1);
        }
        __syncthreads();
        if (tid < 64) {
            int h0 = s_hist[4*tid], h1 = s_hist[4*tid+1], h2 = s_hist[4*tid+2], h3 = s_hist[4*tid+3];
            int s4 = h0 + h1 + h2 + h3, inc = s4;
            #pragma unroll
            for (int off = 1; off < 64; off <<= 1) {
                int t = __shfl_up(inc, off);
                if (tid >= off) inc += t;
            }
            int base = inc - s4;
            if (krem >= base && krem < inc) {
                if      (krem < base + h0)           { s_selb = 4*tid;   s_selk = krem - base; }
                else if (krem < base + h0 + h1)      { s_selb = 4*tid+1; s_selk = krem - base - h0; }
                else if (krem < base + h0 + h1 + h2) { s_selb = 4*tid+2; s_selk = krem - base - h0 - h1; }
                else                                 { s_selb = 4*tid+3; s_selk = krem - base - h0 - h1 - h2; }
            }
        }
        __syncthreads();
        prefix |= ((unsigned)s_selb) << shift;
        krem = s_selk;
        if (pass == 0) { if (tid == 0) s_tn = 0; }
    }

    // ---- resolve ties (equal fv) by original index: stable order ----
    __syncthreads();
    for (int s = tid; s < SDIM; s += NT) {
        if (s_fv[s] == prefix) {
            int slot = atomicAdd(&s_tn, 1);
            if (slot < 64) s_tbuf[slot] = s;
        }
    }
    __syncthreads();
    if (tid == 0) {
        int ntie = s_tn;
        int js = s_tbuf[0];
        if (ntie > 1) {
            for (int a = 0; a < ntie; ++a) {
                int c = s_tbuf[a], r = 0;
                for (int b2 = 0; b2 < ntie; ++b2) r += (int)(s_tbuf[b2] < c);
                if (r == krem) js = c;
            }
        }
        out_items[n] = (float)s_samp[js];
        const int pos = rank_k + 1;            // similarity = pos/500
        atomicAdd(&ws_acc[0], pos);            // mean(similarity)
        atomicAdd(&ws_acc[1], abs(pos - 250)); // |sim-0.5| = |pos-250|/500
    }
}

__global__ __launch_bounds__(64) void rs_fin(const int* __restrict__ ws_acc,
                                             float* __restrict__ out_scal, int N)
{
    if (threadIdx.x == 0) {
        const double denom = (double)SDIM * (double)N;
        out_scal[0] = (float)((double)ws_acc[1] / denom);  // similarity_loss
        out_scal[1] = (float)((double)ws_acc[0] / denom);  // mean(similarity)
    }
}

extern "C" void kernel_launch(void* const* d_in, const int* in_sizes, int n_in,
                              void* d_out, int out_size, void* d_ws, size_t ws_size,
                              hipStream_t stream) {
    const int*   need_replace  = (const int*)d_in[0];
    const float* union_feature = (const float*)d_in[1];
    const float* all_items     = (const float*)d_in[2];
    const int*   sample_items  = (const int*)d_in[3];
    const float* Wm            = (const float*)d_in[4];
    const float* bv            = (const float*)d_in[5];
    const float* gumbel_u      = (const float*)d_in[6];

    const int N = in_sizes[0] / 2;  // 4096

    float* out       = (float*)d_out;
    float* out_items = out;                       // N
    float* out_feat  = out + N;                   // N*64
    float* out_scal  = out + N + (long)N * DDIM;  // 2 scalars
    int*   ws_acc    = (int*)d_ws;                // 2 ints

    hipMemsetAsync(ws_acc, 0, 2 * sizeof(int), stream);
    rs_main<<<N, NT, 0, stream>>>(need_replace, union_feature, all_items,
                                  sample_items, Wm, bv, gumbel_u,
                                  out_items, out_feat, ws_acc);
    rs_fin<<<1, 64, 0, stream>>>(ws_acc, out_scal, N);
}

// Round 9
// 81.508 us; speedup vs baseline: 1.7246x; 1.6957x over previous
//
#include <hip/hip_runtime.h>

#define SDIM 500
#define DDIM 64
#define NT   256

__device__ __forceinline__ unsigned ford(float x) {
    unsigned u = __float_as_uint(x);
    return u ^ ((unsigned)((int)u >> 31) | 0x80000000u);
}

__device__ __forceinline__ float dot16(float4 a0, float4 a1, float4 a2, float4 a3,
                                       float4 b0, float4 b1, float4 b2, float4 b3) {
    return a0.x*b0.x + a0.y*b0.y + a0.z*b0.z + a0.w*b0.w
         + a1.x*b1.x + a1.y*b1.y + a1.z*b1.z + a1.w*b1.w
         + a2.x*b2.x + a2.y*b2.y + a2.z*b2.z + a2.w*b2.w
         + a3.x*b3.x + a3.y*b3.y + a3.z*b3.z + a3.w*b3.w;
}

// EXACT round-3 structure (81.4 us measured: one row per 256-thread block,
// 4 waves cooperate, per-row ws_sim store + separate reduce kernel, NO
// global atomics) + ONE lever: depth-1 prefetch in the score gather loop.
__global__ __launch_bounds__(NT) void rs_main(
    const int* __restrict__ need_replace,    // (N,2)
    const float* __restrict__ union_feature, // (N,128)
    const float* __restrict__ all_items,     // (n_items,64)
    const int* __restrict__ sample_items,    // (n_users,500)
    const float* __restrict__ Wm,            // (64,128)
    const float* __restrict__ bv,            // (64)
    const float* __restrict__ gumbel_u,      // (N,500)
    float* __restrict__ out_items,           // (N)
    float* __restrict__ out_feat,            // (N,64)
    float* __restrict__ ws_sim)              // (N)
{
    __shared__ __align__(16) float s_uf[128];
    __shared__ __align__(16) float s_uif[DDIM];
    __shared__ unsigned s_fv[SDIM];   // order-preserving uint of rank_score
    __shared__ float    s_key[SDIM];  // replace_score (raw, pre-gumbel)
    __shared__ int      s_samp[SDIM];
    __shared__ int      s_hist[256];
    __shared__ float    s_mv[4];
    __shared__ int      s_mi[4];
    __shared__ int      s_cnt4[4];
    __shared__ int      s_selb, s_selk, s_k, s_tn;
    __shared__ int      s_tbuf[64];

    const int n    = blockIdx.x;
    const int tid  = threadIdx.x;
    const int wid  = tid >> 6;
    const int part = tid & 3, quad = tid >> 2;

    const int user = need_replace[2 * n];
    const int item = need_replace[2 * n + 1];
    const int*   samp_row = sample_items + (long)user * SDIM;
    const float* gur      = gumbel_u + (long)n * SDIM;

    // ---- stage (coalesced) ----
    if (tid < 128) s_uf[tid] = union_feature[(long)n * 128 + tid];
    for (int s = tid; s < SDIM; s += NT) s_samp[s] = samp_row[s];
    const float4* ir = (const float4*)(all_items + (long)item * DDIM) + part * 4;
    const float4 wiA = ir[0], wiB = ir[1], wiC = ir[2], wiD = ir[3];
    __syncthreads();

    // ---- uif = W @ uf + b : 4 lanes per output row ----
    {
        const float4* wr4 = (const float4*)(Wm + (long)quad * 128);
        const float4* uf4 = (const float4*)s_uf;
        float acc = 0.f;
        #pragma unroll
        for (int q = 0; q < 8; ++q) {
            float4 w4 = wr4[part + q * 4];
            float4 u4 = uf4[part + q * 4];
            acc += w4.x * u4.x + w4.y * u4.y + w4.z * u4.z + w4.w * u4.w;
        }
        acc += __shfl_xor(acc, 1);
        acc += __shfl_xor(acc, 2);
        if (part == 0) s_uif[quad] = acc + bv[quad];
    }
    __syncthreads();
    const float4* ur = (const float4*)s_uif + part * 4;
    const float4 wuA = ur[0], wuB = ur[1], wuC = ur[2], wuD = ur[3];

    // ---- score phase: quad per sample row, depth-1 prefetched gathers ----
    float4 f0, f1, f2, f3;
    {
        const float4* p = (const float4*)(all_items + (long)s_samp[quad] * DDIM) + part * 4;
        f0 = p[0]; f1 = p[1]; f2 = p[2]; f3 = p[3];
    }
    #pragma unroll
    for (int i = 0; i < 8; ++i) {
        const int s = i * 64 + quad;
        float4 g0 = f0, g1 = f1, g2 = f2, g3 = f3;
        if (i < 7) {
            const int sn = s + 64;
            const bool actn = (sn < SDIM);
            const int idxn = s_samp[actn ? sn : 0];
            const float4* q = (const float4*)(all_items + (long)idxn * DDIM) + part * 4;
            if (actn) { g0 = q[0]; g1 = q[1]; g2 = q[2]; g3 = q[3]; }
        }
        const bool act = (s < SDIM);
        float a0 = dot16(f0, f1, f2, f3, wiA, wiB, wiC, wiD);
        float a1 = dot16(f0, f1, f2, f3, wuA, wuB, wuC, wuD);
        a0 += __shfl_xor(a0, 1); a0 += __shfl_xor(a0, 2);
        a1 += __shfl_xor(a1, 1); a1 += __shfl_xor(a1, 2);
        if (act && part == 0) { s_fv[s] = ford(a0); s_key[s] = a1; }
        f0 = g0; f1 = g1; f2 = g2; f3 = g3;
    }
    __syncthreads();

    // ---- argmax of replace_score + gumbel (first-max tie-break) ----
    {
        float bvv = -__builtin_inff();
        int   bii = SDIM;
        for (int s = tid; s < SDIM; s += NT) {
            float u = gur[s];
            float g = -logf(-logf(u * (1.0f - 2e-7f) + 1e-7f));
            float v = s_key[s] + g;
            if (v > bvv) { bvv = v; bii = s; }
        }
        #pragma unroll
        for (int off = 1; off < 64; off <<= 1) {
            float v2 = __shfl_xor(bvv, off); int i2 = __shfl_xor(bii, off);
            if (v2 > bvv || (v2 == bvv && i2 < bii)) { bvv = v2; bii = i2; }
        }
        if ((tid & 63) == 0) { s_mv[wid] = bvv; s_mi[wid] = bii; }
        __syncthreads();
        if (tid == 0) {
            float mv = s_mv[0]; int mi = s_mi[0];
            #pragma unroll
            for (int w = 1; w < 4; ++w) {
                float v2 = s_mv[w]; int i2 = s_mi[w];
                if (v2 > mv || (v2 == mv && i2 < mi)) { mv = v2; mi = i2; }
            }
            s_k = mi;
        }
        __syncthreads();
    }
    const int k = s_k;

    // ---- overlap: feature output = all_items[samp[k]] ----
    {
        const int src = s_samp[k];
        if (tid < DDIM)
            out_feat[(long)n * DDIM + tid] = all_items[(long)src * DDIM + tid];
    }

    // ---- rank_k = stable rank of element k ----
    int rank_k;
    {
        const unsigned fvk = s_fv[k];
        int cnt = 0;
        for (int s = tid; s < SDIM; s += NT) {
            unsigned v = s_fv[s];
            cnt += (int)((v < fvk) | ((v == fvk) & (s < k)));
        }
        #pragma unroll
        for (int off = 1; off < 64; off <<= 1) cnt += __shfl_xor(cnt, off);
        if ((tid & 63) == 0) s_cnt4[wid] = cnt;
        __syncthreads();
        rank_k = s_cnt4[0] + s_cnt4[1] + s_cnt4[2] + s_cnt4[3];
    }

    // ---- radix-select: j* = index of k-th smallest (stable) ----
    unsigned prefix = 0;
    int krem = k;
    for (int pass = 0; pass < 4; ++pass) {
        const int shift = 24 - 8 * pass;
        s_hist[tid] = 0;
        __syncthreads();
        const unsigned himask = pass ? (0xFFFFFFFFu << (shift + 8)) : 0u;
        for (int s = tid; s < SDIM; s += NT) {
            unsigned v = s_fv[s];
            if ((v & himask) == prefix) atomicAdd(&s_hist[(v >> shift) & 0xFF], 1);
        }
        __syncthreads();
        if (tid < 64) {
            int h0 = s_hist[4*tid], h1 = s_hist[4*tid+1], h2 = s_hist[4*tid+2], h3 = s_hist[4*tid+3];
            int s4 = h0 + h1 + h2 + h3, inc = s4;
            #pragma unroll
            for (int off = 1; off < 64; off <<= 1) {
                int t = __shfl_up(inc, off);
                if (tid >= off) inc += t;
            }
            int base = inc - s4;
            if (krem >= base && krem < inc) {
                if      (krem < base + h0)           { s_selb = 4*tid;   s_selk = krem - base; }
                else if (krem < base + h0 + h1)      { s_selb = 4*tid+1; s_selk = krem - base - h0; }
                else if (krem < base + h0 + h1 + h2) { s_selb = 4*tid+2; s_selk = krem - base - h0 - h1; }
                else                                 { s_selb = 4*tid+3; s_selk = krem - base - h0 - h1 - h2; }
            }
        }
        __syncthreads();
        prefix |= ((unsigned)s_selb) << shift;
        krem = s_selk;
        if (pass == 0) { if (tid == 0) s_tn = 0; }
    }

    // ---- resolve ties (equal fv) by original index: stable order ----
    __syncthreads();
    for (int s = tid; s < SDIM; s += NT) {
        if (s_fv[s] == prefix) {
            int slot = atomicAdd(&s_tn, 1);
            if (slot < 64) s_tbuf[slot] = s;
        }
    }
    __syncthreads();
    if (tid == 0) {
        int ntie = s_tn;
        int js = s_tbuf[0];
        if (ntie > 1) {
            for (int a = 0; a < ntie; ++a) {
                int c = s_tbuf[a], r = 0;
                for (int b2 = 0; b2 < ntie; ++b2) r += (int)(s_tbuf[b2] < c);
                if (r == krem) js = c;
            }
        }
        out_items[n] = (float)s_samp[js];
        ws_sim[n]    = (float)(rank_k + 1) / (float)SDIM;
    }
}

__global__ __launch_bounds__(NT) void rs_reduce(
    const float* __restrict__ ws_sim, float* __restrict__ out_scal, int N)
{
    __shared__ float s0[NT], s1[NT];
    int tid = threadIdx.x;
    float a = 0.f, m = 0.f;
    for (int i = tid; i < N; i += NT) {
        float sim = ws_sim[i];
        a += fabsf(sim - 0.5f);
        m += sim;
    }
    s0[tid] = a; s1[tid] = m;
    __syncthreads();
    for (int off = NT / 2; off > 0; off >>= 1) {
        if (tid < off) { s0[tid] += s0[tid + off]; s1[tid] += s1[tid + off]; }
        __syncthreads();
    }
    if (tid == 0) {
        out_scal[0] = s0[0] / (float)N;  // similarity_loss
        out_scal[1] = s1[0] / (float)N;  // mean(similarity)
    }
}

extern "C" void kernel_launch(void* const* d_in, const int* in_sizes, int n_in,
                              void* d_out, int out_size, void* d_ws, size_t ws_size,
                              hipStream_t stream) {
    const int*   need_replace  = (const int*)d_in[0];
    const float* union_feature = (const float*)d_in[1];
    const float* all_items     = (const float*)d_in[2];
    const int*   sample_items  = (const int*)d_in[3];
    const float* Wm            = (const float*)d_in[4];
    const float* bv            = (const float*)d_in[5];
    const float* gumbel_u      = (const float*)d_in[6];

    const int N = in_sizes[0] / 2;  // 4096

    float* out       = (float*)d_out;
    float* out_items = out;                       // N
    float* out_feat  = out + N;                   // N*64
    float* out_scal  = out + N + (long)N * DDIM;  // 2 scalars
    float* ws_sim    = (float*)d_ws;              // N floats

    rs_main<<<N, NT, 0, stream>>>(need_replace, union_feature, all_items,
                                  sample_items, Wm, bv, gumbel_u,
                                  out_items, out_feat, ws_sim);
    rs_reduce<<<1, NT, 0, stream>>>(ws_sim, out_scal, N);
}